// Round 1
// baseline (452.208 us; speedup 1.0000x reference)
//
#include <hip/hip_runtime.h>

// ---------------------------------------------------------------------------
// Soft decision tree forward:
//   d = sigmoid(X @ T^T)  [32768 x 1023]
//   leaf probs = path products (depth 10)
//   logits = probs @ L     [32768 x 1024]
//   out = softmax(logits)
//
// Precision: GEMM1 via 3-term bf16 split (near-fp32 dots), GEMM2 plain bf16,
// everything else f32. Node dim padded 1023 -> 1024 (padded threshold row = 0,
// its d is never read by the tree expansion).
// ---------------------------------------------------------------------------

typedef unsigned short u16;
typedef short bf16x8 __attribute__((ext_vector_type(8)));
typedef float f32x4 __attribute__((ext_vector_type(4)));

#define BATCH 32768
#define DIM   1024
#define NPAD  1024

// ---- bf16 helpers (RN-even) ----
__device__ __forceinline__ u16 f2bf(float f) {
    union { float f; unsigned u; } v; v.f = f;
    unsigned r = v.u + 0x7FFFu + ((v.u >> 16) & 1u);
    return (u16)(r >> 16);
}
__device__ __forceinline__ float bf2f(u16 h) {
    union { unsigned u; float f; } v; v.u = ((unsigned)h) << 16;
    return v.f;
}

// ---- async global->LDS, 16B per lane (dest = wave-uniform base + lane*16) ----
__device__ __forceinline__ void gl16(const u16* g, u16* l) {
    __builtin_amdgcn_global_load_lds(
        (const __attribute__((address_space(1))) unsigned int*)g,
        (__attribute__((address_space(3))) unsigned int*)l, 16, 0, 0);
}

// ---------------------------------------------------------------------------
// prep: X f32 -> Xhi + Xlo bf16 (hi/lo split)
// ---------------------------------------------------------------------------
__global__ __launch_bounds__(256) void prep_x(const float4* __restrict__ x4,
                                              u16* __restrict__ xhi,
                                              u16* __restrict__ xlo, int n4) {
    int stride = gridDim.x * blockDim.x;
    for (int i = blockIdx.x * blockDim.x + threadIdx.x; i < n4; i += stride) {
        float4 v = x4[i];
        u16 h0 = f2bf(v.x), h1 = f2bf(v.y), h2 = f2bf(v.z), h3 = f2bf(v.w);
        u16 l0 = f2bf(v.x - bf2f(h0)), l1 = f2bf(v.y - bf2f(h1));
        u16 l2 = f2bf(v.z - bf2f(h2)), l3 = f2bf(v.w - bf2f(h3));
        *(ushort4*)&xhi[(size_t)i * 4] = make_ushort4(h0, h1, h2, h3);
        *(ushort4*)&xlo[(size_t)i * 4] = make_ushort4(l0, l1, l2, l3);
    }
}

// ---------------------------------------------------------------------------
// prep: thresholds (1023x1024 f32) -> Thi/Tlo bf16 [1024][1024], row 1023 = 0
// ---------------------------------------------------------------------------
__global__ __launch_bounds__(256) void prep_t(const float* __restrict__ t,
                                              u16* __restrict__ thi,
                                              u16* __restrict__ tlo) {
    int i = blockIdx.x * 256 + threadIdx.x;        // 0 .. 1024*1024-1
    int node = i >> 10;
    float v = (node < 1023) ? t[i] : 0.0f;
    u16 h = f2bf(v);
    thi[i] = h;
    tlo[i] = f2bf(v - bf2f(h));
}

// ---------------------------------------------------------------------------
// prep: leaf_predictions (1024x1024 f32) -> LT bf16 transposed [out][leaf]
// ---------------------------------------------------------------------------
__global__ __launch_bounds__(256) void prep_lt(const float* __restrict__ L,
                                               u16* __restrict__ LT) {
    __shared__ float tile[32][33];
    int bx = blockIdx.x, by = blockIdx.y;
    int tx = threadIdx.x & 31, ty = threadIdx.x >> 5;   // 32 x 8
#pragma unroll
    for (int r = 0; r < 4; r++)
        tile[ty + 8 * r][tx] = L[(size_t)(by * 32 + ty + 8 * r) * 1024 + bx * 32 + tx];
    __syncthreads();
#pragma unroll
    for (int r = 0; r < 4; r++)
        LT[(size_t)(bx * 32 + ty + 8 * r) * 1024 + by * 32 + tx] =
            f2bf(tile[tx][ty + 8 * r]);
}

// ---------------------------------------------------------------------------
// GEMM1 (split bf16, 3 MFMA terms) + sigmoid -> dpair {d, 1-d} bf16x2
// 128x128 tile, BK=32, 4 waves each 64x64 (4x4 frags of 16x16x32)
// ---------------------------------------------------------------------------
__global__ __launch_bounds__(256, 2) void gemm1_kernel(
    const u16* __restrict__ Xhi, const u16* __restrict__ Xlo,
    const u16* __restrict__ Thi, const u16* __restrict__ Tlo,
    ushort2* __restrict__ dpair) {
    __shared__ __align__(16) u16 sAh[4096], sAl[4096], sBh[4096], sBl[4096];

    const int t = threadIdx.x, w = t >> 6, l = t & 63;
    const int rb = blockIdx.y << 7, cb = blockIdx.x << 7;

    // staging: thread -> (row, 8-elem segment); load0 rows w*32..+15, load1 +16
    const int r0  = (w << 5) + (l >> 2);
    const int seg = (l & 3) << 3;
    const size_t gA0 = (size_t)(rb + r0) * DIM + seg;
    const size_t gA1 = gA0 + (size_t)16 * DIM;
    const size_t gB0 = (size_t)(cb + r0) * DIM + seg;
    const size_t gB1 = gB0 + (size_t)16 * DIM;
    const int ld0 = w << 10;        // ushort index: w*1024 (= w*2048 bytes)
    const int ld1 = ld0 + 512;

    f32x4 acc[4][4];
#pragma unroll
    for (int m = 0; m < 4; m++)
#pragma unroll
        for (int n = 0; n < 4; n++) acc[m][n] = (f32x4){0.f, 0.f, 0.f, 0.f};

    const int wm = w >> 1, wn = w & 1;
    const int g8 = (l >> 4) << 3;   // k-group * 8
    const int mr = l & 15;

    for (int k0 = 0; k0 < DIM; k0 += 32) {
        gl16(Xhi + gA0 + k0, sAh + ld0);
        gl16(Xhi + gA1 + k0, sAh + ld1);
        gl16(Xlo + gA0 + k0, sAl + ld0);
        gl16(Xlo + gA1 + k0, sAl + ld1);
        gl16(Thi + gB0 + k0, sBh + ld0);
        gl16(Thi + gB1 + k0, sBh + ld1);
        gl16(Tlo + gB0 + k0, sBl + ld0);
        gl16(Tlo + gB1 + k0, sBl + ld1);
        __syncthreads();            // drains vmcnt -> LDS tiles ready

        bf16x8 ah[4], al[4], bh[4], bl[4];
#pragma unroll
        for (int m = 0; m < 4; m++) {
            int off = ((wm << 6) + (m << 4) + mr) * 32 + g8;
            ah[m] = *(const bf16x8*)(sAh + off);
            al[m] = *(const bf16x8*)(sAl + off);
        }
#pragma unroll
        for (int n = 0; n < 4; n++) {
            int off = ((wn << 6) + (n << 4) + mr) * 32 + g8;
            bh[n] = *(const bf16x8*)(sBh + off);
            bl[n] = *(const bf16x8*)(sBl + off);
        }
#pragma unroll
        for (int m = 0; m < 4; m++)
#pragma unroll
            for (int n = 0; n < 4; n++) {
                acc[m][n] = __builtin_amdgcn_mfma_f32_16x16x32_bf16(ah[m], bh[n], acc[m][n], 0, 0, 0);
                acc[m][n] = __builtin_amdgcn_mfma_f32_16x16x32_bf16(ah[m], bl[n], acc[m][n], 0, 0, 0);
                acc[m][n] = __builtin_amdgcn_mfma_f32_16x16x32_bf16(al[m], bh[n], acc[m][n], 0, 0, 0);
            }
        __syncthreads();            // protect LDS before next stage
    }

    // epilogue: sigmoid, store {d, 1-d}
    const int fq = (l >> 4) << 2;
#pragma unroll
    for (int m = 0; m < 4; m++)
#pragma unroll
        for (int j = 0; j < 4; j++) {
            int grow = rb + (wm << 6) + (m << 4) + fq + j;
#pragma unroll
            for (int n = 0; n < 4; n++) {
                int gcol = cb + (wn << 6) + (n << 4) + mr;
                float s = acc[m][n][j];
                float d = 1.0f / (1.0f + __expf(-s));
                dpair[(size_t)grow * NPAD + gcol] = make_ushort2(f2bf(d), f2bf(1.0f - d));
            }
        }
}

// ---------------------------------------------------------------------------
// tree expansion: one wave per row; lane l owns leaves l*16 .. l*16+15
// leaf L: level λ uses node (2^λ-1)+(L>>(10-λ)), bit (L>>(9-λ))&1 (0->d,1->1-d)
// ---------------------------------------------------------------------------
__global__ __launch_bounds__(256) void probs_kernel(const ushort2* __restrict__ dpair,
                                                    u16* __restrict__ probs) {
    const int t = threadIdx.x, w = t >> 6, l = t & 63;
    const int row = (blockIdx.x << 2) + w;
    const ushort2* dp = dpair + (size_t)row * NPAD;

    // shared prefix: levels 0..5 (L>>4 == l)
    float prod = 1.0f;
#pragma unroll
    for (int lev = 0; lev < 6; lev++) {
        int node = (1 << lev) - 1 + (l >> (6 - lev));
        int bit  = (l >> (5 - lev)) & 1;
        ushort2 v = dp[node];
        prod *= bf2f(bit ? v.y : v.x);
    }
    ushort2 n6 = dp[63 + l];
    ushort2 n7[2], n8[4], n9[8];
#pragma unroll
    for (int j = 0; j < 2; j++) n7[j] = dp[127 + 2 * l + j];
#pragma unroll
    for (int j = 0; j < 4; j++) n8[j] = dp[255 + 4 * l + j];
#pragma unroll
    for (int j = 0; j < 8; j++) n9[j] = dp[511 + 8 * l + j];

    u16 outv[16];
#pragma unroll
    for (int j = 0; j < 16; j++) {
        float f6 = bf2f((j >> 3) ? n6.y : n6.x);
        ushort2 v7 = n7[j >> 3];       float f7 = bf2f(((j >> 2) & 1) ? v7.y : v7.x);
        ushort2 v8 = n8[j >> 2];       float f8 = bf2f(((j >> 1) & 1) ? v8.y : v8.x);
        ushort2 v9 = n9[j >> 1];       float f9 = bf2f((j & 1) ? v9.y : v9.x);
        outv[j] = f2bf(prod * f6 * f7 * f8 * f9);
    }
    ushort4* po = (ushort4*)(probs + (size_t)row * 1024 + (l << 4));
#pragma unroll
    for (int q = 0; q < 4; q++)
        po[q] = make_ushort4(outv[4 * q], outv[4 * q + 1], outv[4 * q + 2], outv[4 * q + 3]);
}

// ---------------------------------------------------------------------------
// GEMM2 (plain bf16): logits = probs @ LT^T  -> d_out (f32)
// ---------------------------------------------------------------------------
__global__ __launch_bounds__(256, 2) void gemm2_kernel(
    const u16* __restrict__ P, const u16* __restrict__ LT, float* __restrict__ out) {
    __shared__ __align__(16) u16 sA[4096], sB[4096];

    const int t = threadIdx.x, w = t >> 6, l = t & 63;
    const int rb = blockIdx.y << 7, cb = blockIdx.x << 7;
    const int r0  = (w << 5) + (l >> 2);
    const int seg = (l & 3) << 3;
    const size_t gA0 = (size_t)(rb + r0) * 1024 + seg;
    const size_t gA1 = gA0 + (size_t)16 * 1024;
    const size_t gB0 = (size_t)(cb + r0) * 1024 + seg;
    const size_t gB1 = gB0 + (size_t)16 * 1024;
    const int ld0 = w << 10, ld1 = (w << 10) + 512;

    f32x4 acc[4][4];
#pragma unroll
    for (int m = 0; m < 4; m++)
#pragma unroll
        for (int n = 0; n < 4; n++) acc[m][n] = (f32x4){0.f, 0.f, 0.f, 0.f};

    const int wm = w >> 1, wn = w & 1;
    const int g8 = (l >> 4) << 3;
    const int mr = l & 15;

    for (int k0 = 0; k0 < 1024; k0 += 32) {
        gl16(P + gA0 + k0, sA + ld0);
        gl16(P + gA1 + k0, sA + ld1);
        gl16(LT + gB0 + k0, sB + ld0);
        gl16(LT + gB1 + k0, sB + ld1);
        __syncthreads();

        bf16x8 a[4], b[4];
#pragma unroll
        for (int m = 0; m < 4; m++)
            a[m] = *(const bf16x8*)(sA + ((wm << 6) + (m << 4) + mr) * 32 + g8);
#pragma unroll
        for (int n = 0; n < 4; n++)
            b[n] = *(const bf16x8*)(sB + ((wn << 6) + (n << 4) + mr) * 32 + g8);
#pragma unroll
        for (int m = 0; m < 4; m++)
#pragma unroll
            for (int n = 0; n < 4; n++)
                acc[m][n] = __builtin_amdgcn_mfma_f32_16x16x32_bf16(a[m], b[n], acc[m][n], 0, 0, 0);
        __syncthreads();
    }

    const int fq = (l >> 4) << 2;
#pragma unroll
    for (int m = 0; m < 4; m++)
#pragma unroll
        for (int j = 0; j < 4; j++) {
            int grow = rb + (wm << 6) + (m << 4) + fq + j;
#pragma unroll
            for (int n = 0; n < 4; n++) {
                int gcol = cb + (wn << 6) + (n << 4) + mr;
                out[(size_t)grow * 1024 + gcol] = acc[m][n][j];
            }
        }
}

// ---------------------------------------------------------------------------
// row softmax in-place on d_out (one block per row, 256 threads x float4)
// ---------------------------------------------------------------------------
__global__ __launch_bounds__(256) void softmax_kernel(float* __restrict__ out) {
    __shared__ float red[8];
    const int t = threadIdx.x, w = t >> 6, l = t & 63;
    float4* o4 = (float4*)out;
    const size_t base = (size_t)blockIdx.x * 256;
    float4 v = o4[base + t];

    float m = fmaxf(fmaxf(v.x, v.y), fmaxf(v.z, v.w));
#pragma unroll
    for (int off = 32; off; off >>= 1) m = fmaxf(m, __shfl_xor(m, off));
    if (l == 0) red[w] = m;
    __syncthreads();
    m = fmaxf(fmaxf(red[0], red[1]), fmaxf(red[2], red[3]));

    float e0 = __expf(v.x - m), e1 = __expf(v.y - m);
    float e2 = __expf(v.z - m), e3 = __expf(v.w - m);
    float s = e0 + e1 + e2 + e3;
#pragma unroll
    for (int off = 32; off; off >>= 1) s += __shfl_xor(s, off);
    if (l == 0) red[4 + w] = s;
    __syncthreads();
    s = red[4] + red[5] + red[6] + red[7];
    float inv = 1.0f / s;
    o4[base + t] = make_float4(e0 * inv, e1 * inv, e2 * inv, e3 * inv);
}

// ---------------------------------------------------------------------------
extern "C" void kernel_launch(void* const* d_in, const int* in_sizes, int n_in,
                              void* d_out, int out_size, void* d_ws, size_t ws_size,
                              hipStream_t stream) {
    const float* x  = (const float*)d_in[0];
    const float* ft = (const float*)d_in[1];
    const float* lp = (const float*)d_in[2];
    float* out = (float*)d_out;
    char* ws = (char*)d_ws;

    // ws layout (bytes):
    //   Xhi 64Mi | Xlo 64Mi | Thi 2Mi | Tlo 2Mi | LT 2Mi | dpair 128Mi | probs 64Mi
    u16* Xhi = (u16*)ws;
    u16* Xlo = Xhi + (size_t)BATCH * DIM;
    u16* Thi = (u16*)(ws + (size_t)134217728);
    u16* Tlo = Thi + (size_t)NPAD * DIM;
    u16* LT  = Tlo + (size_t)NPAD * DIM;
    ushort2* dpair = (ushort2*)(ws + (size_t)134217728 + 3 * 2097152);
    u16* probs = (u16*)(ws + (size_t)134217728 + 3 * 2097152 + (size_t)BATCH * NPAD * 4);

    prep_x<<<4096, 256, 0, stream>>>((const float4*)x, Xhi, Xlo, BATCH * DIM / 4);
    prep_t<<<4096, 256, 0, stream>>>(ft, Thi, Tlo);
    prep_lt<<<dim3(32, 32), 256, 0, stream>>>(lp, LT);
    gemm1_kernel<<<dim3(8, 256), 256, 0, stream>>>(Xhi, Xlo, Thi, Tlo, dpair);
    probs_kernel<<<8192, 256, 0, stream>>>(dpair, probs);
    gemm2_kernel<<<dim3(8, 256), 256, 0, stream>>>(probs, LT, out);
    softmax_kernel<<<32768, 256, 0, stream>>>(out);
}